// Round 5
// baseline (692.593 us; speedup 1.0000x reference)
//
#include <hip/hip_runtime.h>
#include <math.h>

// ---------------------------------------------------------------------------
// GAT encoder: 3 GATConv layers (H=4,4,1) + ELU + global max pool.
// CSR-by-dst build WITH self-loops materialized, once per call. Per layer:
//   gemm_att:  z = h @ W (fp32, LDS x-tile, BM=64, W reg double-buffer,
//              capped unroll), fused a_s/a_d epilogue
//   k_weights: edge-parallel raw softmax weights exp(lrelu(as[src]+ad[dst]))
//              written head-transposed (coalesced); random gathers hidden by TLP
//   aggregate: wave-per-(node,head); coalesced col+w reads, per-lane denom,
//              readlane-broadcast 8-deep pipelined row gather. No LDS/barriers.
//              Layer 2 fuses the pooled atomicMax.
// Final: decode encoded max pool.
// ---------------------------------------------------------------------------

__device__ __forceinline__ float lrelu(float x) { return x > 0.f ? x : 0.2f * x; }

__device__ __forceinline__ float readlane_f(float v, int l) {
    return __uint_as_float((unsigned)__builtin_amdgcn_readlane((int)__float_as_uint(v), l));
}

// ----------------------------- CSR build -----------------------------------
__global__ void k_count(const int* __restrict__ dst, int E, int* __restrict__ deg) {
    int e = blockIdx.x * 256 + threadIdx.x;
    if (e < E) atomicAdd(&deg[dst[e]], 1);
}

// rowptr/cursor include +1 slot per node for the self-loop
__global__ void k_scan(const int* __restrict__ deg, int* __restrict__ rowptr,
                       int* __restrict__ cursor, int N) {
    __shared__ int sums[1024];
    const int t = threadIdx.x;
    const int per = (N + 1023) >> 10;
    const int b0 = t * per;
    const int b1 = min(b0 + per, N);
    int s = 0;
    for (int i = b0; i < b1; i++) s += deg[i] + 1;
    sums[t] = s;
    __syncthreads();
    for (int off = 1; off < 1024; off <<= 1) {
        int v = (t >= off) ? sums[t - off] : 0;
        __syncthreads();
        sums[t] += v;
        __syncthreads();
    }
    int run = (t == 0) ? 0 : sums[t - 1];
    for (int i = b0; i < b1; i++) {
        rowptr[i] = run;
        cursor[i] = run;
        run += deg[i] + 1;
    }
    if (t == 1023) rowptr[N] = sums[1023];
}

__global__ void k_selfloop(int* __restrict__ cursor, int* __restrict__ col,
                           int* __restrict__ dstv, int N) {
    int n = blockIdx.x * 256 + threadIdx.x;
    if (n < N) {
        int p = atomicAdd(&cursor[n], 1);
        col[p] = n;
        dstv[p] = n;
    }
}

__global__ void k_scatter(const int* __restrict__ src, const int* __restrict__ dst, int E,
                          int* __restrict__ cursor, int* __restrict__ col,
                          int* __restrict__ dstv) {
    int e = blockIdx.x * 256 + threadIdx.x;
    if (e < E) {
        int d = dst[e];
        int p = atomicAdd(&cursor[d], 1);
        col[p] = src[e];
        dstv[p] = d;
    }
}

// ----------------------------- GEMM + attention coefs -----------------------
// Z[N,COLS] = X[N,K] @ W[K,COLS]; a_s[n,h] = <z[n,h,:], att_src[h,:]>, same a_d.
// BM rows/block, 256 threads, thread owns 4 cols x RPG rows. W rows are
// double-buffered in registers (wc/wn), outer k-quad loop NOT unrolled.
// launch_bounds(256,3): 170-VGPR cap guarantees no scratch spill.
template <int K, int COLS, int BM>
__global__ __launch_bounds__(256, 3) void k_gemm_att(
    const float* __restrict__ X, const float* __restrict__ W,
    const float* __restrict__ att_src, const float* __restrict__ att_dst,
    float* __restrict__ Z, float* __restrict__ As, float* __restrict__ Ad, int N) {
    constexpr int C4 = COLS / 4;     // threads per row-strip
    constexpr int NG = 256 / C4;     // row groups
    constexpr int RPG = BM / NG;     // rows per thread
    constexpr int BK = 64;
    constexpr int SK = BK + 4;       // LDS stride (floats), keeps 16B alignment
    constexpr int H = COLS / 64;
    __shared__ float xs[BM * SK];

    const int tid = threadIdx.x;
    const int c4 = tid % C4;
    const int rg = tid / C4;
    const int n0 = blockIdx.x * BM;

    float4 acc[RPG];
#pragma unroll
    for (int j = 0; j < RPG; j++) acc[j] = make_float4(0.f, 0.f, 0.f, 0.f);

    float4 wc[4], wn[4];
#pragma unroll
    for (int i = 0; i < 4; i++)
        wc[i] = *reinterpret_cast<const float4*>(W + (size_t)i * COLS + c4 * 4);

    for (int kb = 0; kb < K; kb += BK) {
        __syncthreads();
        constexpr int PASSES = BM / 16;
#pragma unroll
        for (int p = 0; p < PASSES; p++) {
            const int lin = p * 256 + tid;
            const int r = lin >> 4;
            const int f = lin & 15;
            float4 v = make_float4(0.f, 0.f, 0.f, 0.f);
            const int row = n0 + r;
            if (row < N)
                v = *reinterpret_cast<const float4*>(X + (size_t)row * K + kb + f * 4);
            *reinterpret_cast<float4*>(&xs[r * SK + f * 4]) = v;
        }
        __syncthreads();
#pragma unroll 1
        for (int kk = 0; kk < BK; kk += 4) {
            const int kn = (kb + kk + 4) & (K - 1);
#pragma unroll
            for (int i = 0; i < 4; i++)
                wn[i] = *reinterpret_cast<const float4*>(W + (size_t)(kn + i) * COLS + c4 * 4);
#pragma unroll
            for (int j = 0; j < RPG; j++) {
                const float4 xv = *reinterpret_cast<const float4*>(&xs[(rg + NG * j) * SK + kk]);
                acc[j].x = fmaf(xv.x, wc[0].x, acc[j].x);
                acc[j].y = fmaf(xv.x, wc[0].y, acc[j].y);
                acc[j].z = fmaf(xv.x, wc[0].z, acc[j].z);
                acc[j].w = fmaf(xv.x, wc[0].w, acc[j].w);
                acc[j].x = fmaf(xv.y, wc[1].x, acc[j].x);
                acc[j].y = fmaf(xv.y, wc[1].y, acc[j].y);
                acc[j].z = fmaf(xv.y, wc[1].z, acc[j].z);
                acc[j].w = fmaf(xv.y, wc[1].w, acc[j].w);
                acc[j].x = fmaf(xv.z, wc[2].x, acc[j].x);
                acc[j].y = fmaf(xv.z, wc[2].y, acc[j].y);
                acc[j].z = fmaf(xv.z, wc[2].z, acc[j].z);
                acc[j].w = fmaf(xv.z, wc[2].w, acc[j].w);
                acc[j].x = fmaf(xv.w, wc[3].x, acc[j].x);
                acc[j].y = fmaf(xv.w, wc[3].y, acc[j].y);
                acc[j].z = fmaf(xv.w, wc[3].z, acc[j].z);
                acc[j].w = fmaf(xv.w, wc[3].w, acc[j].w);
            }
#pragma unroll
            for (int i = 0; i < 4; i++) wc[i] = wn[i];
        }
    }

    const float4 as4 = *reinterpret_cast<const float4*>(att_src + c4 * 4);
    const float4 ad4 = *reinterpret_cast<const float4*>(att_dst + c4 * 4);

#pragma unroll
    for (int j = 0; j < RPG; j++) {
        const int row = n0 + rg + NG * j;
        float ps = acc[j].x * as4.x + acc[j].y * as4.y + acc[j].z * as4.z + acc[j].w * as4.w;
        float pd = acc[j].x * ad4.x + acc[j].y * ad4.y + acc[j].z * ad4.z + acc[j].w * ad4.w;
#pragma unroll
        for (int off = 1; off < 16; off <<= 1) {
            ps += __shfl_xor(ps, off, 64);
            pd += __shfl_xor(pd, off, 64);
        }
        if (row < N) {
            *reinterpret_cast<float4*>(Z + (size_t)row * COLS + c4 * 4) = acc[j];
            if ((c4 & 15) == 0) {
                As[(size_t)row * H + (c4 >> 4)] = ps;
                Ad[(size_t)row * H + (c4 >> 4)] = pd;
            }
        }
    }
}

// ----------------------------- edge weights ---------------------------------
// Raw (unnormalized) softmax weights, head-transposed planes wgt[h*Et + p].
// Random As/Ad gathers are hidden by massive edge-level parallelism.
template <int H>
__global__ void k_weights(const float* __restrict__ As, const float* __restrict__ Ad,
                          const int* __restrict__ col, const int* __restrict__ dstv,
                          float* __restrict__ wgt, int Et) {
    int p = blockIdx.x * 256 + threadIdx.x;
    if (p >= Et) return;
    const int s = col[p];
    const int n = dstv[p];
    if constexpr (H == 4) {
        const float4 a = *reinterpret_cast<const float4*>(As + (size_t)s * 4);
        const float4 d = *reinterpret_cast<const float4*>(Ad + (size_t)n * 4);
        wgt[p]              = __expf(lrelu(a.x + d.x));
        wgt[Et + p]         = __expf(lrelu(a.y + d.y));
        wgt[2 * (size_t)Et + p] = __expf(lrelu(a.z + d.z));
        wgt[3 * (size_t)Et + p] = __expf(lrelu(a.w + d.w));
    } else {
        wgt[p] = __expf(lrelu(As[s] + Ad[n]));
    }
}

// ----------------------------- global max pool helpers -----------------------
__device__ __forceinline__ unsigned fenc(float f) {
    unsigned u = __float_as_uint(f);
    return (u & 0x80000000u) ? ~u : (u | 0x80000000u);
}

// ----------------------------- aggregate -------------------------------------
// Wave-synchronous: one wave per (node, head). Coalesced col/w chunk loads,
// per-lane denom (wave-reduced once), readlane-broadcast 8-deep row gather.
template <int H, bool DO_ELU, bool POOL>
__global__ __launch_bounds__(256) void k_aggregate(
    const float* __restrict__ Z, const float* __restrict__ wgt,
    const int* __restrict__ rowptr, const int* __restrict__ col,
    const float* __restrict__ bias, float* __restrict__ out,
    const int* __restrict__ batch, unsigned* __restrict__ enc, int N, int Et) {
    constexpr int COLS = H * 64;
    const int tid = threadIdx.x;
    const int wv = tid >> 6;
    const int lane = tid & 63;

    int n, h;
    if constexpr (H == 4) {
        n = blockIdx.x;
        h = wv;
    } else {
        n = blockIdx.x * 4 + wv;
        h = 0;
        if (n >= N) return;
    }

    const int start = rowptr[n];
    const int total = rowptr[n + 1] - start;   // includes self-loop
    const int* __restrict__ cp = col + start;
    const float* __restrict__ wp = wgt + (size_t)h * Et + start;
    const float* __restrict__ Zc = Z + h * 64 + lane;

    float acc = 0.f, denom = 0.f;

    for (int base = 0; base < total; base += 64) {
        const int cnt = min(64, total - base);
        const int i = base + lane;
        int s = 0;
        float w = 0.f;
        if (i < total) {
            s = cp[i];
            w = wp[i];
        }
        denom += w;

        int jj = 0;
        for (; jj + 8 <= cnt; jj += 8) {
            int sb[8];
            float wb[8], zb[8];
#pragma unroll
            for (int u = 0; u < 8; u++) {
                sb[u] = __builtin_amdgcn_readlane(s, jj + u);
                wb[u] = readlane_f(w, jj + u);
            }
#pragma unroll
            for (int u = 0; u < 8; u++) zb[u] = Zc[(size_t)sb[u] * COLS];
#pragma unroll
            for (int u = 0; u < 8; u++) acc = fmaf(wb[u], zb[u], acc);
        }
        for (; jj + 4 <= cnt; jj += 4) {
            int sb[4];
            float wb[4], zb[4];
#pragma unroll
            for (int u = 0; u < 4; u++) {
                sb[u] = __builtin_amdgcn_readlane(s, jj + u);
                wb[u] = readlane_f(w, jj + u);
            }
#pragma unroll
            for (int u = 0; u < 4; u++) zb[u] = Zc[(size_t)sb[u] * COLS];
#pragma unroll
            for (int u = 0; u < 4; u++) acc = fmaf(wb[u], zb[u], acc);
        }
        for (; jj < cnt; jj++) {
            const int s0 = __builtin_amdgcn_readlane(s, jj);
            const float w0 = readlane_f(w, jj);
            acc = fmaf(w0, Zc[(size_t)s0 * COLS], acc);
        }
    }

#pragma unroll
    for (int off = 1; off < 64; off <<= 1) denom += __shfl_xor(denom, off, 64);

    float ov = acc / (denom + 1e-16f) + bias[h * 64 + lane];
    if (DO_ELU) ov = (ov > 0.f) ? ov : expm1f(ov);

    if constexpr (POOL) {
        const int g = batch[n];
        atomicMax(&enc[g * 64 + lane], fenc(ov));
    } else {
        out[(size_t)n * COLS + h * 64 + lane] = ov;
    }
}

__global__ void k_decode(const unsigned* __restrict__ enc, float* __restrict__ out, int M) {
    int id = blockIdx.x * 256 + threadIdx.x;
    if (id < M) {
        unsigned e = enc[id];
        unsigned u = (e & 0x80000000u) ? (e & 0x7FFFFFFFu) : ~e;
        out[id] = __uint_as_float(u);
    }
}

// ----------------------------- launch ---------------------------------------
extern "C" void kernel_launch(void* const* d_in, const int* in_sizes, int n_in,
                              void* d_out, int out_size, void* d_ws, size_t ws_size,
                              hipStream_t stream) {
    const float* x = (const float*)d_in[0];
    const int* edge_index = (const int*)d_in[1];
    const int* batch = (const int*)d_in[2];
    const float* W0 = (const float*)d_in[3];
    const float* as0 = (const float*)d_in[4];
    const float* ad0 = (const float*)d_in[5];
    const float* b0 = (const float*)d_in[6];
    const float* W1 = (const float*)d_in[7];
    const float* as1 = (const float*)d_in[8];
    const float* ad1 = (const float*)d_in[9];
    const float* b1 = (const float*)d_in[10];
    const float* W2 = (const float*)d_in[11];
    const float* as2 = (const float*)d_in[12];
    const float* ad2 = (const float*)d_in[13];
    const float* b2 = (const float*)d_in[14];

    const int N = in_sizes[0] / 64;   // nodes
    const int E = in_sizes[1] / 2;    // edges (no self-loops)
    const int G = out_size / 64;      // graphs
    const int Et = E + N;             // edges incl. self-loops

    const int* srcs = edge_index;
    const int* dsts = edge_index + E;

    char* p = (char*)d_ws;
    auto alloc = [&](size_t bytes) {
        void* r = (void*)p;
        p += (bytes + 255) & ~(size_t)255;
        return r;
    };
    float* Z  = (float*)alloc((size_t)N * 256 * 4);  // GEMM output
    float* Hb = (float*)alloc((size_t)N * 256 * 4);  // hidden activations
    float* As = (float*)alloc((size_t)N * 4 * 4);
    float* Ad = (float*)alloc((size_t)N * 4 * 4);
    int* deg = (int*)alloc((size_t)N * 4);
    int* rowptr = (int*)alloc((size_t)(N + 1) * 4);
    int* cursor = (int*)alloc((size_t)N * 4);
    int* col = (int*)alloc((size_t)Et * 4);
    int* dstv = (int*)alloc((size_t)Et * 4);
    float* wgt = (float*)alloc((size_t)Et * 4 * 4);
    unsigned* enc = (unsigned*)alloc((size_t)G * 64 * 4);

    hipMemsetAsync(deg, 0, (size_t)N * 4, stream);
    hipMemsetAsync(enc, 0, (size_t)G * 64 * 4, stream);

    const int eb = (E + 255) / 256;
    const int nb = (N + 255) / 256;
    const int tb = (Et + 255) / 256;
    k_count<<<eb, 256, 0, stream>>>(dsts, E, deg);
    k_scan<<<1, 1024, 0, stream>>>(deg, rowptr, cursor, N);
    k_selfloop<<<nb, 256, 0, stream>>>(cursor, col, dstv, N);
    k_scatter<<<eb, 256, 0, stream>>>(srcs, dsts, E, cursor, col, dstv);

    const int gb = (N + 63) / 64;
    // Layer 0: in 64, H=4 concat -> 256, ELU
    k_gemm_att<64, 256, 64><<<gb, 256, 0, stream>>>(x, W0, as0, ad0, Z, As, Ad, N);
    k_weights<4><<<tb, 256, 0, stream>>>(As, Ad, col, dstv, wgt, Et);
    k_aggregate<4, true, false><<<N, 256, 0, stream>>>(Z, wgt, rowptr, col, b0, Hb,
                                                       nullptr, nullptr, N, Et);
    // Layer 1: in 256, H=4 concat -> 256, ELU
    k_gemm_att<256, 256, 64><<<gb, 256, 0, stream>>>(Hb, W1, as1, ad1, Z, As, Ad, N);
    k_weights<4><<<tb, 256, 0, stream>>>(As, Ad, col, dstv, wgt, Et);
    k_aggregate<4, true, false><<<N, 256, 0, stream>>>(Z, wgt, rowptr, col, b1, Hb,
                                                       nullptr, nullptr, N, Et);
    // Layer 2: in 256, H=1 -> 64, no ELU, fused global max pool
    k_gemm_att<256, 64, 64><<<gb, 256, 0, stream>>>(Hb, W2, as2, ad2, Z, As, Ad, N);
    k_weights<1><<<tb, 256, 0, stream>>>(As, Ad, col, dstv, wgt, Et);
    k_aggregate<1, false, true><<<(N + 3) / 4, 256, 0, stream>>>(Z, wgt, rowptr, col, b2,
                                                                 nullptr, batch, enc, N, Et);
    // Decode pooled maxima
    k_decode<<<(G * 64 + 255) / 256, 256, 0, stream>>>(enc, (float*)d_out, G * 64);
}

// Round 6
// 690.394 us; speedup vs baseline: 1.0032x; 1.0032x over previous
//
#include <hip/hip_runtime.h>
#include <math.h>

// ---------------------------------------------------------------------------
// GAT encoder: 3 GATConv layers (H=4,4,1) + ELU + global max pool.
// GEMMs run on matrix cores via bf16x3 split emulation (hi/lo bf16 pair per
// fp32 operand; hi*hi + hi*lo + lo*hi with fp32 MFMA accumulate ~ fp32 GEMM,
// rel err ~2^-17). mfma_f32_32x32x16_bf16, 128x128 block, 4 waves x 64x64.
// As/Ad computed algebraically: a_s[n,h] = x[n] . (W @ att_src[h]) -> thin GEMV.
// Aggregate: wave-per-(node,head) softmax gather (R5 structure), now emitting
// bf16 hi/lo activation planes for the next layer's MFMA GEMM.
// ---------------------------------------------------------------------------

typedef __attribute__((ext_vector_type(8))) short short8v;
typedef __attribute__((ext_vector_type(16))) float f32x16;

__device__ __forceinline__ float lrelu(float x) { return x > 0.f ? x : 0.2f * x; }

__device__ __forceinline__ unsigned short f2bf(float x) {  // RNE
    unsigned u = __float_as_uint(x);
    return (unsigned short)((u + 0x7FFFu + ((u >> 16) & 1u)) >> 16);
}
__device__ __forceinline__ float bf2f(unsigned short h) {
    return __uint_as_float(((unsigned)h) << 16);
}
__device__ __forceinline__ float readlane_f(float v, int l) {
    return __uint_as_float((unsigned)__builtin_amdgcn_readlane((int)__float_as_uint(v), l));
}

// ----------------------------- CSR build -----------------------------------
__global__ void k_count(const int* __restrict__ dst, int E, int* __restrict__ deg) {
    int e = blockIdx.x * 256 + threadIdx.x;
    if (e < E) atomicAdd(&deg[dst[e]], 1);
}

// rowptr/cursor include +1 slot per node for the self-loop
__global__ void k_scan(const int* __restrict__ deg, int* __restrict__ rowptr,
                       int* __restrict__ cursor, int N) {
    __shared__ int sums[1024];
    const int t = threadIdx.x;
    const int per = (N + 1023) >> 10;
    const int b0 = t * per;
    const int b1 = min(b0 + per, N);
    int s = 0;
    for (int i = b0; i < b1; i++) s += deg[i] + 1;
    sums[t] = s;
    __syncthreads();
    for (int off = 1; off < 1024; off <<= 1) {
        int v = (t >= off) ? sums[t - off] : 0;
        __syncthreads();
        sums[t] += v;
        __syncthreads();
    }
    int run = (t == 0) ? 0 : sums[t - 1];
    for (int i = b0; i < b1; i++) {
        rowptr[i] = run;
        cursor[i] = run;
        run += deg[i] + 1;
    }
    if (t == 1023) rowptr[N] = sums[1023];
}

__global__ void k_selfloop(int* __restrict__ cursor, int* __restrict__ col,
                           int* __restrict__ dstv, int N) {
    int n = blockIdx.x * 256 + threadIdx.x;
    if (n < N) {
        int p = atomicAdd(&cursor[n], 1);
        col[p] = n;
        dstv[p] = n;
    }
}

__global__ void k_scatter(const int* __restrict__ src, const int* __restrict__ dst, int E,
                          int* __restrict__ cursor, int* __restrict__ col,
                          int* __restrict__ dstv) {
    int e = blockIdx.x * 256 + threadIdx.x;
    if (e < E) {
        int d = dst[e];
        int p = atomicAdd(&cursor[d], 1);
        col[p] = src[e];
        dstv[p] = d;
    }
}

// ----------------------------- converts --------------------------------------
__global__ void k_conv(const float* __restrict__ in, unsigned short* __restrict__ hi,
                       unsigned short* __restrict__ lo, int M) {
    int i = blockIdx.x * 256 + threadIdx.x;
    if (i < M) {
        float x = in[i];
        unsigned short h = f2bf(x);
        hi[i] = h;
        lo[i] = f2bf(x - bf2f(h));
    }
}

// W[k][C] -> Wt hi/lo [C][K]
template <int K, int C>
__global__ void k_wconv(const float* __restrict__ W, unsigned short* __restrict__ thi,
                        unsigned short* __restrict__ tlo) {
    int i = blockIdx.x * 256 + threadIdx.x;
    if (i < K * C) {
        int c = i / K, k = i % K;
        float x = W[(size_t)k * C + c];
        unsigned short h = f2bf(x);
        thi[i] = h;
        tlo[i] = f2bf(x - bf2f(h));
    }
}

// vs[h][k] = sum_cl W[k][h*64+cl]*att_src[h][cl]; vd likewise
template <int K, int C, int H>
__global__ void k_attvec(const float* __restrict__ W, const float* __restrict__ as,
                         const float* __restrict__ ad, float* __restrict__ vs,
                         float* __restrict__ vd) {
    int k = blockIdx.x * 256 + threadIdx.x;
    if (k >= K) return;
    for (int h = 0; h < H; h++) {
        float s = 0.f, d = 0.f;
        for (int cl = 0; cl < 64; cl++) {
            float w = W[(size_t)k * C + h * 64 + cl];
            s = fmaf(w, as[h * 64 + cl], s);
            d = fmaf(w, ad[h * 64 + cl], d);
        }
        vs[h * K + k] = s;
        vd[h * K + k] = d;
    }
}

// ----------------------------- As/Ad GEMV ------------------------------------
// As[n,h] = x[n,:] . vs[h,:]; one wave per node.
template <int K, int H, bool SPLIT>
__global__ __launch_bounds__(256) void k_att(
    const float* __restrict__ X, const unsigned short* __restrict__ Xhi,
    const unsigned short* __restrict__ Xlo, const float* __restrict__ vs,
    const float* __restrict__ vd, float* __restrict__ As, float* __restrict__ Ad, int N) {
    constexpr int CPL = K / 64;
    const int n = blockIdx.x * 4 + (threadIdx.x >> 6);
    const int lane = threadIdx.x & 63;
    if (n >= N) return;

    float xv[CPL];
    if constexpr (SPLIT) {
        if constexpr (CPL == 4) {
            const uint2 uh = *reinterpret_cast<const uint2*>(Xhi + (size_t)n * K + lane * 4);
            const uint2 ul = *reinterpret_cast<const uint2*>(Xlo + (size_t)n * K + lane * 4);
            xv[0] = bf2f((unsigned short)(uh.x & 0xffff)) + bf2f((unsigned short)(ul.x & 0xffff));
            xv[1] = bf2f((unsigned short)(uh.x >> 16)) + bf2f((unsigned short)(ul.x >> 16));
            xv[2] = bf2f((unsigned short)(uh.y & 0xffff)) + bf2f((unsigned short)(ul.y & 0xffff));
            xv[3] = bf2f((unsigned short)(uh.y >> 16)) + bf2f((unsigned short)(ul.y >> 16));
        } else {
            for (int i = 0; i < CPL; i++)
                xv[i] = bf2f(Xhi[(size_t)n * K + lane * CPL + i]) +
                        bf2f(Xlo[(size_t)n * K + lane * CPL + i]);
        }
    } else {
        if constexpr (CPL == 4) {
            const float4 v = *reinterpret_cast<const float4*>(X + (size_t)n * K + lane * 4);
            xv[0] = v.x; xv[1] = v.y; xv[2] = v.z; xv[3] = v.w;
        } else {
            for (int i = 0; i < CPL; i++) xv[i] = X[(size_t)n * K + lane * CPL + i];
        }
    }

#pragma unroll
    for (int h = 0; h < H; h++) {
        float ps = 0.f, pd = 0.f;
#pragma unroll
        for (int i = 0; i < CPL; i++) {
            ps = fmaf(xv[i], vs[h * K + lane * CPL + i], ps);
            pd = fmaf(xv[i], vd[h * K + lane * CPL + i], pd);
        }
#pragma unroll
        for (int off = 1; off < 64; off <<= 1) {
            ps += __shfl_xor(ps, off, 64);
            pd += __shfl_xor(pd, off, 64);
        }
        if (lane == 0) {
            As[(size_t)n * H + h] = ps;
            Ad[(size_t)n * H + h] = pd;
        }
    }
}

// ----------------------------- MFMA GEMM (bf16x3) ----------------------------
// Z[N,COLS] = X @ W. A = hi/lo bf16 planes [N][K]; B = Wt hi/lo [COLS][K].
// Block: 128 rows x BN cols, 4 waves, wave tile 64 x WN, BK=32.
// LDS stride 40 bf16 (80B): b128 reads hit the 4-cycle floor, no pileup.
template <int K, int COLS, int BN, int WN>
__global__ __launch_bounds__(256) void k_gemm_mx(
    const unsigned short* __restrict__ Ahi, const unsigned short* __restrict__ Alo,
    const unsigned short* __restrict__ Bhi, const unsigned short* __restrict__ Blo,
    float* __restrict__ Z, int N) {
    constexpr int BM = 128, LD = 40;
    constexpr int WM = 64;
    constexpr int WAVES_N = BN / WN;
    constexpr int MW = WM / 32, NW = WN / 32;
    static_assert(BN == 128 || BN == 64, "");
    __shared__ unsigned short sa[2][BM * LD];
    __shared__ unsigned short sb[2][BN * LD];

    const int tid = threadIdx.x;
    const int n0 = blockIdx.x * BM;
    const int c0 = blockIdx.y * BN;
    const int wid = tid >> 6, lane = tid & 63;
    const int wr = wid / WAVES_N, wc = wid % WAVES_N;

    f32x16 acc[MW][NW];
#pragma unroll
    for (int m = 0; m < MW; m++)
#pragma unroll
        for (int n = 0; n < NW; n++)
#pragma unroll
            for (int i = 0; i < 16; i++) acc[m][n][i] = 0.f;

    const int srow = tid >> 2, schk = tid & 3;  // staging row / 8-ushort chunk

    for (int kb = 0; kb < K; kb += 32) {
        __syncthreads();
#pragma unroll
        for (int rr = 0; rr < 2; rr++) {
            const int r = srow + rr * 64;
            const int row = n0 + r;
            short8v vh = {0, 0, 0, 0, 0, 0, 0, 0}, vl = {0, 0, 0, 0, 0, 0, 0, 0};
            if (row < N) {
                vh = *reinterpret_cast<const short8v*>(Ahi + (size_t)row * K + kb + schk * 8);
                vl = *reinterpret_cast<const short8v*>(Alo + (size_t)row * K + kb + schk * 8);
            }
            *reinterpret_cast<short8v*>(&sa[0][r * LD + schk * 8]) = vh;
            *reinterpret_cast<short8v*>(&sa[1][r * LD + schk * 8]) = vl;
        }
#pragma unroll
        for (int rr = 0; rr < (BN == 128 ? 2 : 1); rr++) {
            const int cc = srow + rr * 64;
            const short8v vh =
                *reinterpret_cast<const short8v*>(Bhi + (size_t)(c0 + cc) * K + kb + schk * 8);
            const short8v vl =
                *reinterpret_cast<const short8v*>(Blo + (size_t)(c0 + cc) * K + kb + schk * 8);
            *reinterpret_cast<short8v*>(&sb[0][cc * LD + schk * 8]) = vh;
            *reinterpret_cast<short8v*>(&sb[1][cc * LD + schk * 8]) = vl;
        }
        __syncthreads();
#pragma unroll
        for (int ks = 0; ks < 2; ks++) {
            const int koff = ks * 16 + (lane >> 5) * 8;
            short8v ah[MW], al[MW], bh[NW], bl[NW];
#pragma unroll
            for (int m = 0; m < MW; m++) {
                const int ar = wr * WM + m * 32 + (lane & 31);
                ah[m] = *reinterpret_cast<const short8v*>(&sa[0][ar * LD + koff]);
                al[m] = *reinterpret_cast<const short8v*>(&sa[1][ar * LD + koff]);
            }
#pragma unroll
            for (int n = 0; n < NW; n++) {
                const int br = wc * WN + n * 32 + (lane & 31);
                bh[n] = *reinterpret_cast<const short8v*>(&sb[0][br * LD + koff]);
                bl[n] = *reinterpret_cast<const short8v*>(&sb[1][br * LD + koff]);
            }
#pragma unroll
            for (int m = 0; m < MW; m++)
#pragma unroll
                for (int n = 0; n < NW; n++) {
                    acc[m][n] = __builtin_amdgcn_mfma_f32_32x32x16_bf16(ah[m], bh[n], acc[m][n], 0, 0, 0);
                    acc[m][n] = __builtin_amdgcn_mfma_f32_32x32x16_bf16(ah[m], bl[n], acc[m][n], 0, 0, 0);
                    acc[m][n] = __builtin_amdgcn_mfma_f32_32x32x16_bf16(al[m], bh[n], acc[m][n], 0, 0, 0);
                }
        }
    }

    // epilogue: C/D layout col=lane&31, row=(reg&3)+8*(reg>>2)+4*(lane>>5)
    const int colb = c0 + wc * WN + (lane & 31);
    const int rowb = n0 + wr * WM + 4 * (lane >> 5);
#pragma unroll
    for (int m = 0; m < MW; m++)
#pragma unroll
        for (int n = 0; n < NW; n++)
#pragma unroll
            for (int r = 0; r < 16; r++) {
                const int row = rowb + m * 32 + (r & 3) + 8 * (r >> 2);
                if (row < N) Z[(size_t)row * COLS + colb + n * 32] = acc[m][n][r];
            }
}

// ----------------------------- edge weights ---------------------------------
template <int H>
__global__ void k_weights(const float* __restrict__ As, const float* __restrict__ Ad,
                          const int* __restrict__ col, const int* __restrict__ dstv,
                          float* __restrict__ wgt, int Et) {
    int p = blockIdx.x * 256 + threadIdx.x;
    if (p >= Et) return;
    const int s = col[p];
    const int n = dstv[p];
    if constexpr (H == 4) {
        const float4 a = *reinterpret_cast<const float4*>(As + (size_t)s * 4);
        const float4 d = *reinterpret_cast<const float4*>(Ad + (size_t)n * 4);
        wgt[p]                  = __expf(lrelu(a.x + d.x));
        wgt[(size_t)Et + p]     = __expf(lrelu(a.y + d.y));
        wgt[2 * (size_t)Et + p] = __expf(lrelu(a.z + d.z));
        wgt[3 * (size_t)Et + p] = __expf(lrelu(a.w + d.w));
    } else {
        wgt[p] = __expf(lrelu(As[s] + Ad[n]));
    }
}

// ----------------------------- global max pool helpers -----------------------
__device__ __forceinline__ unsigned fenc(float f) {
    unsigned u = __float_as_uint(f);
    return (u & 0x80000000u) ? ~u : (u | 0x80000000u);
}

// ----------------------------- aggregate -------------------------------------
// Wave per (node, head). OUTMODE 0: write bf16 hi/lo planes; 1: pooled atomicMax.
template <int H, bool DO_ELU, int OUTMODE>
__global__ __launch_bounds__(256) void k_aggregate(
    const float* __restrict__ Z, const float* __restrict__ wgt,
    const int* __restrict__ rowptr, const int* __restrict__ col,
    const float* __restrict__ bias, unsigned short* __restrict__ ohi,
    unsigned short* __restrict__ olo, const int* __restrict__ batch,
    unsigned* __restrict__ enc, int N, int Et) {
    constexpr int COLS = H * 64;
    const int tid = threadIdx.x;
    const int wv = tid >> 6;
    const int lane = tid & 63;

    int n, h;
    if constexpr (H == 4) {
        n = blockIdx.x;
        h = wv;
    } else {
        n = blockIdx.x * 4 + wv;
        h = 0;
        if (n >= N) return;
    }

    const int start = rowptr[n];
    const int total = rowptr[n + 1] - start;  // includes self-loop
    const int* __restrict__ cp = col + start;
    const float* __restrict__ wp = wgt + (size_t)h * Et + start;
    const float* __restrict__ Zc = Z + h * 64 + lane;

    float acc = 0.f, denom = 0.f;

    for (int base = 0; base < total; base += 64) {
        const int cnt = min(64, total - base);
        const int i = base + lane;
        int s = 0;
        float w = 0.f;
        if (i < total) {
            s = cp[i];
            w = wp[i];
        }
        denom += w;

        int jj = 0;
        for (; jj + 8 <= cnt; jj += 8) {
            int sb[8];
            float wb[8], zb[8];
#pragma unroll
            for (int u = 0; u < 8; u++) {
                sb[u] = __builtin_amdgcn_readlane(s, jj + u);
                wb[u] = readlane_f(w, jj + u);
            }
#pragma unroll
            for (int u = 0; u < 8; u++) zb[u] = Zc[(size_t)sb[u] * COLS];
#pragma unroll
            for (int u = 0; u < 8; u++) acc = fmaf(wb[u], zb[u], acc);
        }
        for (; jj + 4 <= cnt; jj += 4) {
            int sb[4];
            float wb[4], zb[4];
#pragma unroll
            for (int u = 0; u < 4; u++) {
                sb[u] = __builtin_amdgcn_readlane(s, jj + u);
                wb[u] = readlane_f(w, jj + u);
            }
#pragma unroll
            for (int u = 0; u < 4; u++) zb[u] = Zc[(size_t)sb[u] * COLS];
#pragma unroll
            for (int u = 0; u < 4; u++) acc = fmaf(wb[u], zb[u], acc);
        }
        for (; jj < cnt; jj++) {
            const int s0 = __builtin_amdgcn_readlane(s, jj);
            const float w0 = readlane_f(w, jj);
            acc = fmaf(w0, Zc[(size_t)s0 * COLS], acc);
        }
    }

#pragma unroll
    for (int off = 1; off < 64; off <<= 1) denom += __shfl_xor(denom, off, 64);

    float ov = acc / (denom + 1e-16f) + bias[h * 64 + lane];
    if (DO_ELU) ov = (ov > 0.f) ? ov : expm1f(ov);

    if constexpr (OUTMODE == 1) {
        const int g = batch[n];
        atomicMax(&enc[g * 64 + lane], fenc(ov));
    } else {
        const unsigned short hb = f2bf(ov);
        ohi[(size_t)n * COLS + h * 64 + lane] = hb;
        olo[(size_t)n * COLS + h * 64 + lane] = f2bf(ov - bf2f(hb));
    }
}

__global__ void k_decode(const unsigned* __restrict__ enc, float* __restrict__ out, int M) {
    int id = blockIdx.x * 256 + threadIdx.x;
    if (id < M) {
        unsigned e = enc[id];
        unsigned u = (e & 0x80000000u) ? (e & 0x7FFFFFFFu) : ~e;
        out[id] = __uint_as_float(u);
    }
}

// ----------------------------- launch ---------------------------------------
extern "C" void kernel_launch(void* const* d_in, const int* in_sizes, int n_in,
                              void* d_out, int out_size, void* d_ws, size_t ws_size,
                              hipStream_t stream) {
    const float* x = (const float*)d_in[0];
    const int* edge_index = (const int*)d_in[1];
    const int* batch = (const int*)d_in[2];
    const float* W0 = (const float*)d_in[3];
    const float* as0 = (const float*)d_in[4];
    const float* ad0 = (const float*)d_in[5];
    const float* b0 = (const float*)d_in[6];
    const float* W1 = (const float*)d_in[7];
    const float* as1 = (const float*)d_in[8];
    const float* ad1 = (const float*)d_in[9];
    const float* b1 = (const float*)d_in[10];
    const float* W2 = (const float*)d_in[11];
    const float* as2 = (const float*)d_in[12];
    const float* ad2 = (const float*)d_in[13];
    const float* b2 = (const float*)d_in[14];

    const int N = in_sizes[0] / 64;  // nodes
    const int E = in_sizes[1] / 2;   // edges (no self-loops)
    const int G = out_size / 64;     // graphs
    const int Et = E + N;            // edges incl. self-loops

    const int* srcs = edge_index;
    const int* dsts = edge_index + E;

    char* p = (char*)d_ws;
    auto alloc = [&](size_t bytes) {
        void* r = (void*)p;
        p += (bytes + 255) & ~(size_t)255;
        return r;
    };
    float* Z = (float*)alloc((size_t)N * 256 * 4);
    unsigned short* Hbhi = (unsigned short*)alloc((size_t)N * 256 * 2);  // pre-L0: xhi (N*64)
    unsigned short* Hblo = (unsigned short*)alloc((size_t)N * 256 * 2);  // pre-L0: xlo
    float* As = (float*)alloc((size_t)N * 4 * 4);
    float* Ad = (float*)alloc((size_t)N * 4 * 4);
    int* deg = (int*)alloc((size_t)N * 4);
    int* rowptr = (int*)alloc((size_t)(N + 1) * 4);
    int* cursor = (int*)alloc((size_t)N * 4);
    int* col = (int*)alloc((size_t)Et * 4);
    int* dstv = (int*)alloc((size_t)Et * 4);
    float* wgt = (float*)alloc((size_t)Et * 4 * 4);
    unsigned short* wt0h = (unsigned short*)alloc(256 * 64 * 2);
    unsigned short* wt0l = (unsigned short*)alloc(256 * 64 * 2);
    unsigned short* wt1h = (unsigned short*)alloc(256 * 256 * 2);
    unsigned short* wt1l = (unsigned short*)alloc(256 * 256 * 2);
    unsigned short* wt2h = (unsigned short*)alloc(64 * 256 * 2);
    unsigned short* wt2l = (unsigned short*)alloc(64 * 256 * 2);
    float* vs0 = (float*)alloc(4 * 64 * 4);
    float* vd0 = (float*)alloc(4 * 64 * 4);
    float* vs1 = (float*)alloc(4 * 256 * 4);
    float* vd1 = (float*)alloc(4 * 256 * 4);
    float* vs2 = (float*)alloc(256 * 4);
    float* vd2 = (float*)alloc(256 * 4);
    unsigned* enc = (unsigned*)alloc((size_t)G * 64 * 4);

    hipMemsetAsync(deg, 0, (size_t)N * 4, stream);
    hipMemsetAsync(enc, 0, (size_t)G * 64 * 4, stream);

    const int eb = (E + 255) / 256;
    const int nb = (N + 255) / 256;
    const int tb = (Et + 255) / 256;
    k_count<<<eb, 256, 0, stream>>>(dsts, E, deg);
    k_scan<<<1, 1024, 0, stream>>>(deg, rowptr, cursor, N);
    k_selfloop<<<nb, 256, 0, stream>>>(cursor, col, dstv, N);
    k_scatter<<<eb, 256, 0, stream>>>(srcs, dsts, E, cursor, col, dstv);

    // one-time converts / attention projection vectors
    k_conv<<<(N * 64 + 255) / 256, 256, 0, stream>>>(x, Hbhi, Hblo, N * 64);
    k_wconv<64, 256><<<(64 * 256 + 255) / 256, 256, 0, stream>>>(W0, wt0h, wt0l);
    k_wconv<256, 256><<<(256 * 256 + 255) / 256, 256, 0, stream>>>(W1, wt1h, wt1l);
    k_wconv<256, 64><<<(256 * 64 + 255) / 256, 256, 0, stream>>>(W2, wt2h, wt2l);
    k_attvec<64, 256, 4><<<1, 256, 0, stream>>>(W0, as0, ad0, vs0, vd0);
    k_attvec<256, 256, 4><<<1, 256, 0, stream>>>(W1, as1, ad1, vs1, vd1);
    k_attvec<256, 64, 1><<<1, 256, 0, stream>>>(W2, as2, ad2, vs2, vd2);

    const int ab = (N + 3) / 4;
    const int gm = (N + 127) / 128;

    // Layer 0: K=64 -> 256 cols, H=4, ELU
    k_att<64, 4, false><<<ab, 256, 0, stream>>>(x, nullptr, nullptr, vs0, vd0, As, Ad, N);
    k_gemm_mx<64, 256, 128, 64><<<dim3(gm, 2), 256, 0, stream>>>(Hbhi, Hblo, wt0h, wt0l, Z, N);
    k_weights<4><<<tb, 256, 0, stream>>>(As, Ad, col, dstv, wgt, Et);
    k_aggregate<4, true, 0><<<N, 256, 0, stream>>>(Z, wgt, rowptr, col, b0, Hbhi, Hblo,
                                                   nullptr, nullptr, N, Et);
    // Layer 1: K=256 -> 256 cols, H=4, ELU
    k_att<256, 4, true><<<ab, 256, 0, stream>>>(nullptr, Hbhi, Hblo, vs1, vd1, As, Ad, N);
    k_gemm_mx<256, 256, 128, 64><<<dim3(gm, 2), 256, 0, stream>>>(Hbhi, Hblo, wt1h, wt1l, Z, N);
    k_weights<4><<<tb, 256, 0, stream>>>(As, Ad, col, dstv, wgt, Et);
    k_aggregate<4, true, 0><<<N, 256, 0, stream>>>(Z, wgt, rowptr, col, b1, Hbhi, Hblo,
                                                   nullptr, nullptr, N, Et);
    // Layer 2: K=256 -> 64 cols, H=1, no ELU, fused pool
    k_att<256, 1, true><<<ab, 256, 0, stream>>>(nullptr, Hbhi, Hblo, vs2, vd2, As, Ad, N);
    k_gemm_mx<256, 64, 64, 32><<<dim3(gm, 1), 256, 0, stream>>>(Hbhi, Hblo, wt2h, wt2l, Z, N);
    k_weights<1><<<tb, 256, 0, stream>>>(As, Ad, col, dstv, wgt, Et);
    k_aggregate<1, false, 1><<<ab, 256, 0, stream>>>(Z, wgt, rowptr, col, b2, nullptr, nullptr,
                                                     batch, enc, N, Et);
    // Decode pooled maxima
    k_decode<<<(G * 64 + 255) / 256, 256, 0, stream>>>(enc, (float*)d_out, G * 64);
}